// Round 11
// baseline (2119.846 us; speedup 1.0000x reference)
//
#include <hip/hip_runtime.h>
#include <hip/hip_fp16.h>

#define N_JOB 500000
#define N_WORKER 50000
#define E_PRE 4000000
#define E_NXT 4000000
#define E_PROC 2000000

// Aggregation dst windows: 1024 nodes x 489. Src groups: 8 x 65536 (2MB fp16 h).
#define DWBITS 10
#define DW 1024
#define NWD 489
#define G 8
#define NCELL (NWD * G)                // 3912 cells per jj relation
#define CAP_JJ 1280                    // cell mean 1022 + 8 sigma
#define CAP_PR 4608                    // proc window mean 4090 + 8 sigma
// srcb (outdeg) windows: 62 x 8192 u16 locals
#define SWBITS 13
#define SWSZ 8192
#define NSW 62
#define CAP_SR 67584

#define GC_PROC (2 * NCELL)            // 7824
#define GC_SRC  (GC_PROC + NWD)        // 8313
#define GC_TOT  (GC_SRC + 2 * NSW)     // 8437

#define EPB 32768
#define NBJ ((E_PRE + EPB - 1) / EPB)   // 123
#define NBP ((E_PROC + EPB - 1) / EPB)  // 62

__global__ void cursor_init(int* __restrict__ gcur) {
    for (int k = threadIdx.x; k < GC_TOT; k += 1024) {
        if (k < GC_PROC)      gcur[k] = k * CAP_JJ;
        else if (k < GC_SRC)  gcur[k] = (k - GC_PROC) * CAP_PR;
        else                  gcur[k] = (k - GC_SRC) * CAP_SR;
    }
}

// ---------------------------------------------------------------------------
// Partition: block owns 32768 edges of one relation. jj edges histogrammed by
// (dst_window_1024, src_group_64K) -> global reservation -> replay with plain
// stores. jj entry: (dst&1023)<<19 | src. proc: ((dl<<16)|src, eid).
// Also emits u16 src-locals (62x8192 windows) for outdeg.
// ---------------------------------------------------------------------------
__global__ __launch_bounds__(256) void partition_kernel(
        const int* __restrict__ pre_src, const int* __restrict__ pre_dst,
        const int* __restrict__ nxt_src, const int* __restrict__ nxt_dst,
        const int* __restrict__ proc_src, const int* __restrict__ proc_dst,
        int* __restrict__ gcur, unsigned* __restrict__ jjb,
        int2* __restrict__ procb, unsigned short* __restrict__ srcb) {
    __shared__ int cntD[NCELL], basD[NCELL], curD[NCELL];
    __shared__ int cntS[NSW], basS[NSW], curS[NSW];
    int t = threadIdx.x;
    int b = blockIdx.x;
    int rel, lo, hi;
    const int *dstp, *srcp;
    if (b < NBJ) {
        rel = 0; dstp = pre_dst; srcp = pre_src;
        lo = b * EPB; hi = min(lo + EPB, E_PRE);
    } else if (b < 2 * NBJ) {
        rel = 1; b -= NBJ; dstp = nxt_dst; srcp = nxt_src;
        lo = b * EPB; hi = min(lo + EPB, E_NXT);
    } else {
        rel = 2; b -= 2 * NBJ; dstp = proc_dst; srcp = proc_src;
        lo = b * EPB; hi = min(lo + EPB, E_PROC);
    }
    if (rel < 2) {
        for (int k = t; k < NCELL; k += 256) cntD[k] = 0;
        for (int k = t; k < NSW; k += 256) cntS[k] = 0;
        __syncthreads();
        for (int i = lo + t; i < hi; i += 256) {
            int d = dstp[i], s = srcp[i];
            atomicAdd(&cntD[((d >> DWBITS) << 3) | (s >> 16)], 1);
            atomicAdd(&cntS[s >> SWBITS], 1);
        }
        __syncthreads();
        for (int k = t; k < NCELL; k += 256) {
            int c = cntD[k];
            basD[k] = c ? atomicAdd(&gcur[rel * NCELL + k], c) : 0;
            curD[k] = 0;
        }
        for (int k = t; k < NSW; k += 256) {
            int c = cntS[k];
            basS[k] = c ? atomicAdd(&gcur[GC_SRC + rel * NSW + k], c) : 0;
            curS[k] = 0;
        }
        __syncthreads();
        for (int i = lo + t; i < hi; i += 256) {
            int d = dstp[i], s = srcp[i];
            int seg = ((d >> DWBITS) << 3) | (s >> 16);
            int p = basD[seg] + atomicAdd(&curD[seg], 1);
            jjb[p] = ((unsigned)(d & (DW - 1)) << 19) | (unsigned)s;
            int sw = s >> SWBITS;
            int pS = basS[sw] + atomicAdd(&curS[sw], 1);
            srcb[pS] = (unsigned short)(s & (SWSZ - 1));
        }
    } else {
        for (int k = t; k < NWD; k += 256) cntD[k] = 0;
        __syncthreads();
        for (int i = lo + t; i < hi; i += 256)
            atomicAdd(&cntD[dstp[i] >> DWBITS], 1);
        __syncthreads();
        for (int k = t; k < NWD; k += 256) {
            int c = cntD[k];
            basD[k] = c ? atomicAdd(&gcur[GC_PROC + k], c) : 0;
            curD[k] = 0;
        }
        __syncthreads();
        for (int i = lo + t; i < hi; i += 256) {
            int d = dstp[i], s = srcp[i];
            int wd = d >> DWBITS;
            int p = basD[wd] + atomicAdd(&curD[wd], 1);
            procb[p] = make_int2(((d & (DW - 1)) << 16) | s, i);
        }
    }
}

// ---------------------------------------------------------------------------
// outdeg_build: one block per (rel,src-window); LDS histogram of u16 locals,
// writes rsqrt(max(deg,1)) floats.
// ---------------------------------------------------------------------------
__global__ __launch_bounds__(256) void outdeg_build(
        const unsigned short* __restrict__ srcb, const int* __restrict__ gcur,
        float* __restrict__ sc_pre, float* __restrict__ sc_nxt) {
    __shared__ int hist[SWSZ];
    int t = threadIdx.x;
    int rel = blockIdx.x / NSW;
    int w = blockIdx.x % NSW;
    int k = rel * NSW + w;
    int segbase = k * CAP_SR;
    int segend = gcur[GC_SRC + k];
    for (int i = t; i < SWSZ; i += 256) hist[i] = 0;
    __syncthreads();
    int cnt = segend - segbase;
    const unsigned* p2 = (const unsigned*)(srcb + segbase);
    int n2 = cnt >> 1;
    for (int i = t; i < n2; i += 256) {
        unsigned v = p2[i];
        atomicAdd(&hist[v & 0xFFFFu], 1);
        atomicAdd(&hist[v >> 16], 1);
    }
    if (t == 0 && (cnt & 1)) atomicAdd(&hist[srcb[segend - 1]], 1);
    __syncthreads();
    float* scp = rel ? sc_nxt : sc_pre;
    int nlo = w * SWSZ;
    int nloc = min(SWSZ, N_JOB - nlo);
    for (int i = t; i < nloc; i += 256) {
        int d = hist[i];
        scp[nlo + i] = rsqrtf((float)(d < 1 ? 1 : d));
    }
}

__device__ __forceinline__ unsigned pack_h2(float a, float b) {
    __half2 h = __float22half2_rn(make_float2(a, b));
    return *reinterpret_cast<unsigned*>(&h);
}
__device__ __forceinline__ float2 unpack_h2(unsigned u) {
    __half2 h = *reinterpret_cast<__half2*>(&u);
    return __half22float2(h);
}

// ---------------------------------------------------------------------------
// Embedding. HOUT=true: fp16 row. HOUT=false: f32 row (hw).
// ---------------------------------------------------------------------------
template <int F, bool HOUT>
__global__ void embed_kernel(const float* __restrict__ feat, const float* __restrict__ W,
                             const float* __restrict__ b, void* __restrict__ outp, int n) {
    __shared__ float Ws[F * 16];
    __shared__ float bs[16];
    int t = threadIdx.x;
    if (t < F * 16) Ws[t] = W[t];
    if (t < 16) bs[t] = b[t];
    __syncthreads();
    int i = blockIdx.x * blockDim.x + t;
    if (i >= n) return;
    float f[F];
#pragma unroll
    for (int k = 0; k < F; k++) f[k] = feat[(size_t)i * F + k];
    float o[16];
#pragma unroll
    for (int d = 0; d < 16; d++) {
        float s = bs[d];
#pragma unroll
        for (int k = 0; k < F; k++) s += f[k] * Ws[k * 16 + d];
        o[d] = s;
    }
    if (HOUT) {
        uint4* dst = (uint4*)((__half*)outp + (size_t)i * 16);
        dst[0] = make_uint4(pack_h2(o[0], o[1]), pack_h2(o[2], o[3]),
                            pack_h2(o[4], o[5]), pack_h2(o[6], o[7]));
        dst[1] = make_uint4(pack_h2(o[8], o[9]), pack_h2(o[10], o[11]),
                            pack_h2(o[12], o[13]), pack_h2(o[14], o[15]));
    } else {
        float4* dst4 = (float4*)((float*)outp + (size_t)i * 16);
        dst4[0] = make_float4(o[0], o[1], o[2], o[3]);
        dst4[1] = make_float4(o[4], o[5], o[6], o[7]);
        dst4[2] = make_float4(o[8], o[9], o[10], o[11]);
        dst4[3] = make_float4(o[12], o[13], o[14], o[15]);
    }
}

__device__ __forceinline__ void mm_accum(const float* __restrict__ Ws, float4 a, int c, float o[4]) {
#pragma unroll
    for (int g = 0; g < 4; ++g) {
        float a0 = __shfl(a.x, g, 4);
        float a1 = __shfl(a.y, g, 4);
        float a2 = __shfl(a.z, g, 4);
        float a3 = __shfl(a.w, g, 4);
        const float* wr = &Ws[(4 * g) * 16 + c * 4];
#pragma unroll
        for (int j = 0; j < 4; ++j)
            o[j] += a0 * wr[j] + a1 * wr[16 + j] + a2 * wr[32 + j] + a3 * wr[48 + j];
    }
}

// ---------------------------------------------------------------------------
// window_layer: one block per 1024-node dst window; acc/res in LDS; sweeps
// src-group cells in order (0..7) so ALL resident blocks gather from the
// same 2MB h16 slice at any instant -> per-XCD L2 hit. LDS float atomics,
// no global atomics. Phases: pre -> nxt -> sage -> self; matmul into res;
// FINAL scores from LDS res.
// ---------------------------------------------------------------------------
template <bool FINAL>
__global__ __launch_bounds__(256) void window_layer(
        const __half* __restrict__ cur, const float* __restrict__ hwk,
        const unsigned* __restrict__ jjb, const int2* __restrict__ procb,
        const int* __restrict__ gcur,
        const float* __restrict__ sc_pre, const float* __restrict__ sc_nxt,
        const float* __restrict__ Wp, const float* __restrict__ Wn,
        const float* __restrict__ Wng, const float* __restrict__ Wsf,
        const float* __restrict__ bp, const float* __restrict__ bn,
        const float* __restrict__ bsg,
        __half* __restrict__ out, float* __restrict__ scores) {
    __shared__ float acc[DW * 17];     // stride 17: bank-spread for atomics
    __shared__ float res[DW * 16];
    __shared__ int cnt[DW];
    __shared__ float Wl[256];
    __shared__ float bsl[16];
    int t = threadIdx.x;
    int w = blockIdx.x;
    int nlo = w << DWBITS;
    int nloc = min(DW, N_JOB - nlo);
    int c = t & 3, nb = t >> 2;

    // ---------------- phase A: precede-conv ----------------
    for (int i = t; i < DW * 17; i += 256) acc[i] = 0.f;
    for (int i = t; i < DW; i += 256) cnt[i] = 0;
    Wl[t] = Wp[t];
    if (t < 16) bsl[t] = bp[t] + bn[t] + bsg[t];
    __syncthreads();
    for (int g = 0; g < G; ++g) {
        int cell = (w << 3) + g;
        int se = gcur[cell];
        for (int p = cell * CAP_JJ + t; p < se; p += 256) {
            unsigned e = jjb[p];
            int s = (int)(e & 0x7FFFFu);
            int dl = (int)(e >> 19);
            float sc = sc_pre[s];
            const uint4* hp = (const uint4*)(cur + (size_t)s * 16);
            uint4 A = hp[0], B = hp[1];
            float2 f0 = unpack_h2(A.x), f1 = unpack_h2(A.y), f2 = unpack_h2(A.z), f3 = unpack_h2(A.w);
            float2 f4 = unpack_h2(B.x), f5 = unpack_h2(B.y), f6 = unpack_h2(B.z), f7 = unpack_h2(B.w);
            atomicAdd(&cnt[dl], 1);
            float* ap = &acc[dl * 17];
            atomicAdd(ap + 0,  f0.x * sc); atomicAdd(ap + 1,  f0.y * sc);
            atomicAdd(ap + 2,  f1.x * sc); atomicAdd(ap + 3,  f1.y * sc);
            atomicAdd(ap + 4,  f2.x * sc); atomicAdd(ap + 5,  f2.y * sc);
            atomicAdd(ap + 6,  f3.x * sc); atomicAdd(ap + 7,  f3.y * sc);
            atomicAdd(ap + 8,  f4.x * sc); atomicAdd(ap + 9,  f4.y * sc);
            atomicAdd(ap + 10, f5.x * sc); atomicAdd(ap + 11, f5.y * sc);
            atomicAdd(ap + 12, f6.x * sc); atomicAdd(ap + 13, f6.y * sc);
            atomicAdd(ap + 14, f7.x * sc); atomicAdd(ap + 15, f7.y * sc);
        }
        __syncthreads();   // group lockstep
    }
    for (int n = nb; n < nloc; n += 64) {
        float r = rsqrtf((float)(cnt[n] < 1 ? 1 : cnt[n]));
        const float* ap = &acc[n * 17 + c * 4];
        float4 a = make_float4(ap[0] * r, ap[1] * r, ap[2] * r, ap[3] * r);
        float o[4] = {bsl[c * 4 + 0], bsl[c * 4 + 1], bsl[c * 4 + 2], bsl[c * 4 + 3]};
        mm_accum(Wl, a, c, o);
        float* rp = &res[n * 16 + c * 4];
        rp[0] = o[0]; rp[1] = o[1]; rp[2] = o[2]; rp[3] = o[3];
    }
    __syncthreads();

    // ---------------- phase B: next-conv ----------------
    for (int i = t; i < DW * 17; i += 256) acc[i] = 0.f;
    for (int i = t; i < DW; i += 256) cnt[i] = 0;
    Wl[t] = Wn[t];
    __syncthreads();
    for (int g = 0; g < G; ++g) {
        int cell = NCELL + (w << 3) + g;
        int se = gcur[cell];
        for (int p = cell * CAP_JJ + t; p < se; p += 256) {
            unsigned e = jjb[p];
            int s = (int)(e & 0x7FFFFu);
            int dl = (int)(e >> 19);
            float sc = sc_nxt[s];
            const uint4* hp = (const uint4*)(cur + (size_t)s * 16);
            uint4 A = hp[0], B = hp[1];
            float2 f0 = unpack_h2(A.x), f1 = unpack_h2(A.y), f2 = unpack_h2(A.z), f3 = unpack_h2(A.w);
            float2 f4 = unpack_h2(B.x), f5 = unpack_h2(B.y), f6 = unpack_h2(B.z), f7 = unpack_h2(B.w);
            atomicAdd(&cnt[dl], 1);
            float* ap = &acc[dl * 17];
            atomicAdd(ap + 0,  f0.x * sc); atomicAdd(ap + 1,  f0.y * sc);
            atomicAdd(ap + 2,  f1.x * sc); atomicAdd(ap + 3,  f1.y * sc);
            atomicAdd(ap + 4,  f2.x * sc); atomicAdd(ap + 5,  f2.y * sc);
            atomicAdd(ap + 6,  f3.x * sc); atomicAdd(ap + 7,  f3.y * sc);
            atomicAdd(ap + 8,  f4.x * sc); atomicAdd(ap + 9,  f4.y * sc);
            atomicAdd(ap + 10, f5.x * sc); atomicAdd(ap + 11, f5.y * sc);
            atomicAdd(ap + 12, f6.x * sc); atomicAdd(ap + 13, f6.y * sc);
            atomicAdd(ap + 14, f7.x * sc); atomicAdd(ap + 15, f7.y * sc);
        }
        __syncthreads();
    }
    for (int n = nb; n < nloc; n += 64) {
        float r = rsqrtf((float)(cnt[n] < 1 ? 1 : cnt[n]));
        const float* ap = &acc[n * 17 + c * 4];
        float4 a = make_float4(ap[0] * r, ap[1] * r, ap[2] * r, ap[3] * r);
        float o[4] = {0.f, 0.f, 0.f, 0.f};
        mm_accum(Wl, a, c, o);
        float* rp = &res[n * 16 + c * 4];
        rp[0] += o[0]; rp[1] += o[1]; rp[2] += o[2]; rp[3] += o[3];
    }
    __syncthreads();

    // ---------------- phase C: sage-mean over workers ----------------
    for (int i = t; i < DW * 17; i += 256) acc[i] = 0.f;
    for (int i = t; i < DW; i += 256) cnt[i] = 0;
    Wl[t] = Wng[t];
    __syncthreads();
    {
        int sb = w * CAP_PR, se = gcur[GC_PROC + w];
        for (int p = sb + t; p < se; p += 256) {
            int2 e = procb[p];
            int s = e.x & 0xFFFF, dl = e.x >> 16;
            const float4* hp = (const float4*)(hwk + (size_t)s * 16);
            float4 a0 = hp[0], a1 = hp[1], a2 = hp[2], a3 = hp[3];
            atomicAdd(&cnt[dl], 1);
            float* ap = &acc[dl * 17];
            atomicAdd(ap + 0,  a0.x); atomicAdd(ap + 1,  a0.y);
            atomicAdd(ap + 2,  a0.z); atomicAdd(ap + 3,  a0.w);
            atomicAdd(ap + 4,  a1.x); atomicAdd(ap + 5,  a1.y);
            atomicAdd(ap + 6,  a1.z); atomicAdd(ap + 7,  a1.w);
            atomicAdd(ap + 8,  a2.x); atomicAdd(ap + 9,  a2.y);
            atomicAdd(ap + 10, a2.z); atomicAdd(ap + 11, a2.w);
            atomicAdd(ap + 12, a3.x); atomicAdd(ap + 13, a3.y);
            atomicAdd(ap + 14, a3.z); atomicAdd(ap + 15, a3.w);
        }
    }
    __syncthreads();
    for (int n = nb; n < nloc; n += 64) {
        float r = 1.0f / (float)(cnt[n] < 1 ? 1 : cnt[n]);
        const float* ap = &acc[n * 17 + c * 4];
        float4 a = make_float4(ap[0] * r, ap[1] * r, ap[2] * r, ap[3] * r);
        float o[4] = {0.f, 0.f, 0.f, 0.f};
        mm_accum(Wl, a, c, o);
        float* rp = &res[n * 16 + c * 4];
        rp[0] += o[0]; rp[1] += o[1]; rp[2] += o[2]; rp[3] += o[3];
    }
    __syncthreads();

    // ---------------- phase D: self ----------------
    Wl[t] = Wsf[t];
    __syncthreads();
    for (int n = nb; n < nloc; n += 64) {
        uint2 raw = *(const uint2*)(cur + (size_t)(nlo + n) * 16 + c * 4);
        float2 lo2 = unpack_h2(raw.x), hi2 = unpack_h2(raw.y);
        float4 a = make_float4(lo2.x, lo2.y, hi2.x, hi2.y);
        float o[4] = {0.f, 0.f, 0.f, 0.f};
        mm_accum(Wl, a, c, o);
        float* rp = &res[n * 16 + c * 4];
        rp[0] += o[0]; rp[1] += o[1]; rp[2] += o[2]; rp[3] += o[3];
    }
    __syncthreads();

    // ---------------- output ----------------
    if (!FINAL) {
        for (int n = nb; n < nloc; n += 64) {
            const float* rp = &res[n * 16 + c * 4];
            *(uint2*)(out + (size_t)(nlo + n) * 16 + c * 4) =
                make_uint2(pack_h2(rp[0], rp[1]), pack_h2(rp[2], rp[3]));
        }
    } else {
        int sb = w * CAP_PR, se = gcur[GC_PROC + w];
        for (int p = sb + t; p < se; p += 256) {
            int2 e = procb[p];
            int s = e.x & 0xFFFF, dl = e.x >> 16;
            const float4* hp = (const float4*)(hwk + (size_t)s * 16);
            float4 a0 = hp[0], a1 = hp[1], a2 = hp[2], a3 = hp[3];
            const float* rp = &res[dl * 16];
            float d = a0.x * rp[0] + a0.y * rp[1] + a0.z * rp[2] + a0.w * rp[3]
                    + a1.x * rp[4] + a1.y * rp[5] + a1.z * rp[6] + a1.w * rp[7]
                    + a2.x * rp[8] + a2.y * rp[9] + a2.z * rp[10] + a2.w * rp[11]
                    + a3.x * rp[12] + a3.y * rp[13] + a3.z * rp[14] + a3.w * rp[15];
            scores[e.y] = d;
        }
    }
}

extern "C" void kernel_launch(void* const* d_in, const int* in_sizes, int n_in,
                              void* d_out, int out_size, void* d_ws, size_t ws_size,
                              hipStream_t stream) {
    const float* job_feat     = (const float*)d_in[0];
    const float* worker_feat  = (const float*)d_in[1];
    const int*   pre_src      = (const int*)d_in[2];
    const int*   pre_dst      = (const int*)d_in[3];
    const int*   nxt_src      = (const int*)d_in[4];
    const int*   nxt_dst      = (const int*)d_in[5];
    const int*   proc_src     = (const int*)d_in[6];
    const int*   proc_dst     = (const int*)d_in[7];
    const float* W_emb_job    = (const float*)d_in[8];
    const float* b_emb_job    = (const float*)d_in[9];
    const float* W_emb_worker = (const float*)d_in[10];
    const float* b_emb_worker = (const float*)d_in[11];
    const float* W_pre        = (const float*)d_in[12];
    const float* b_pre        = (const float*)d_in[13];
    const float* W_nxt        = (const float*)d_in[14];
    const float* b_nxt        = (const float*)d_in[15];
    const float* W_self       = (const float*)d_in[16];
    const float* W_neigh      = (const float*)d_in[17];
    const float* b_sage       = (const float*)d_in[18];
    float* out = (float*)d_out;

    // Workspace (~97 MB, u32 offsets). srcb aliases h16A/h16B (dead before embed).
    float* ws = (float*)d_ws;
    __half* h16A = (__half*)ws;                              // [0, 4M)
    __half* h16B = (__half*)(ws + 4000000);                  // [4M, 8M)
    float*  hw   = ws + 8000000;                             // [8M, 8.8M)
    float* sc_pre = ws + 8800000;                            // [8.8M, 9.3M)
    float* sc_nxt = ws + 9300000;                            // [9.3M, 9.8M)
    unsigned* jjb = (unsigned*)(ws + 9800000);               // 2*3912*1280 = 10,014,720
    int2*  procb  = (int2*)(ws + 19814720);                  // 489*4608 int2 = 4,506,624 u32
    int*   gcur   = (int*)(ws + 24321344);                   // 8,437 (+pad)
    unsigned short* srcb = (unsigned short*)ws;              // 8,380,416 u16 (aliases h16A/B)

    cursor_init<<<1, 1024, 0, stream>>>(gcur);
    partition_kernel<<<2 * NBJ + NBP, 256, 0, stream>>>(
        pre_src, pre_dst, nxt_src, nxt_dst, proc_src, proc_dst,
        gcur, jjb, procb, srcb);
    outdeg_build<<<2 * NSW, 256, 0, stream>>>(srcb, gcur, sc_pre, sc_nxt);

    embed_kernel<7, true><<<(N_JOB + 255) / 256, 256, 0, stream>>>(
        job_feat, W_emb_job, b_emb_job, h16A, N_JOB);
    embed_kernel<3, false><<<(N_WORKER + 255) / 256, 256, 0, stream>>>(
        worker_feat, W_emb_worker, b_emb_worker, hw, N_WORKER);

    window_layer<false><<<NWD, 256, 0, stream>>>(
        h16A, hw, jjb, procb, gcur, sc_pre, sc_nxt,
        W_pre, W_nxt, W_neigh, W_self, b_pre, b_nxt, b_sage, h16B, nullptr);
    window_layer<true><<<NWD, 256, 0, stream>>>(
        h16B, hw, jjb, procb, gcur, sc_pre, sc_nxt,
        W_pre, W_nxt, W_neigh, W_self, b_pre, b_nxt, b_sage, nullptr, out);
}

// Round 12
// 2070.972 us; speedup vs baseline: 1.0236x; 1.0236x over previous
//
#include <hip/hip_runtime.h>
#include <hip/hip_fp16.h>

#define N_JOB 500000
#define N_WORKER 50000
#define E_PRE 4000000
#define E_NXT 4000000
#define E_PROC 2000000

// Aggregation dst windows: 1024 nodes x 489. Src groups: 8 x 65536 (2MB fp16 h).
#define DWBITS 10
#define DW 1024
#define NWD 489
#define G 8
#define NCELL (NWD * G)                // 3912 cells per jj relation
#define CAP_JJ 1280                    // cell mean 1022 + 8 sigma
#define CAP_PR 4608                    // proc window mean 4090 + 8 sigma
// srcb (outdeg) windows: 62 x 8192 u16 locals
#define SWBITS 13
#define SWSZ 8192
#define NSW 62
#define CAP_SR 67584

#define GC_PROC (2 * NCELL)            // 7824
#define GC_SRC  (GC_PROC + NWD)        // 8313
#define GC_TOT  (GC_SRC + 2 * NSW)     // 8437

#define EPB 32768
#define NBJ ((E_PRE + EPB - 1) / EPB)   // 123
#define NBP ((E_PROC + EPB - 1) / EPB)  // 62

__global__ void cursor_init(int* __restrict__ gcur) {
    for (int k = threadIdx.x; k < GC_TOT; k += 1024) {
        if (k < GC_PROC)      gcur[k] = k * CAP_JJ;
        else if (k < GC_SRC)  gcur[k] = (k - GC_PROC) * CAP_PR;
        else                  gcur[k] = (k - GC_SRC) * CAP_SR;
    }
}

// ---------------------------------------------------------------------------
// Partition: block owns 32768 edges of one relation. jj edges histogrammed by
// (dst_window_1024, src_group_64K) -> global reservation -> replay with plain
// stores. jj entry: (dst&1023)<<19 | src. proc: ((dl<<16)|src, eid).
// Also emits u16 src-locals (62x8192 windows) for outdeg.
// ---------------------------------------------------------------------------
__global__ __launch_bounds__(256) void partition_kernel(
        const int* __restrict__ pre_src, const int* __restrict__ pre_dst,
        const int* __restrict__ nxt_src, const int* __restrict__ nxt_dst,
        const int* __restrict__ proc_src, const int* __restrict__ proc_dst,
        int* __restrict__ gcur, unsigned* __restrict__ jjb,
        int2* __restrict__ procb, unsigned short* __restrict__ srcb) {
    __shared__ int cntD[NCELL], basD[NCELL], curD[NCELL];
    __shared__ int cntS[NSW], basS[NSW], curS[NSW];
    int t = threadIdx.x;
    int b = blockIdx.x;
    int rel, lo, hi;
    const int *dstp, *srcp;
    if (b < NBJ) {
        rel = 0; dstp = pre_dst; srcp = pre_src;
        lo = b * EPB; hi = min(lo + EPB, E_PRE);
    } else if (b < 2 * NBJ) {
        rel = 1; b -= NBJ; dstp = nxt_dst; srcp = nxt_src;
        lo = b * EPB; hi = min(lo + EPB, E_NXT);
    } else {
        rel = 2; b -= 2 * NBJ; dstp = proc_dst; srcp = proc_src;
        lo = b * EPB; hi = min(lo + EPB, E_PROC);
    }
    if (rel < 2) {
        for (int k = t; k < NCELL; k += 256) cntD[k] = 0;
        for (int k = t; k < NSW; k += 256) cntS[k] = 0;
        __syncthreads();
        for (int i = lo + t; i < hi; i += 256) {
            int d = dstp[i], s = srcp[i];
            atomicAdd(&cntD[((d >> DWBITS) << 3) | (s >> 16)], 1);
            atomicAdd(&cntS[s >> SWBITS], 1);
        }
        __syncthreads();
        for (int k = t; k < NCELL; k += 256) {
            int c = cntD[k];
            basD[k] = c ? atomicAdd(&gcur[rel * NCELL + k], c) : 0;
            curD[k] = 0;
        }
        for (int k = t; k < NSW; k += 256) {
            int c = cntS[k];
            basS[k] = c ? atomicAdd(&gcur[GC_SRC + rel * NSW + k], c) : 0;
            curS[k] = 0;
        }
        __syncthreads();
        for (int i = lo + t; i < hi; i += 256) {
            int d = dstp[i], s = srcp[i];
            int seg = ((d >> DWBITS) << 3) | (s >> 16);
            int p = basD[seg] + atomicAdd(&curD[seg], 1);
            jjb[p] = ((unsigned)(d & (DW - 1)) << 19) | (unsigned)s;
            int sw = s >> SWBITS;
            int pS = basS[sw] + atomicAdd(&curS[sw], 1);
            srcb[pS] = (unsigned short)(s & (SWSZ - 1));
        }
    } else {
        for (int k = t; k < NWD; k += 256) cntD[k] = 0;
        __syncthreads();
        for (int i = lo + t; i < hi; i += 256)
            atomicAdd(&cntD[dstp[i] >> DWBITS], 1);
        __syncthreads();
        for (int k = t; k < NWD; k += 256) {
            int c = cntD[k];
            basD[k] = c ? atomicAdd(&gcur[GC_PROC + k], c) : 0;
            curD[k] = 0;
        }
        __syncthreads();
        for (int i = lo + t; i < hi; i += 256) {
            int d = dstp[i], s = srcp[i];
            int wd = d >> DWBITS;
            int p = basD[wd] + atomicAdd(&curD[wd], 1);
            procb[p] = make_int2(((d & (DW - 1)) << 16) | s, i);
        }
    }
}

// ---------------------------------------------------------------------------
// outdeg_build: one block per (rel,src-window); LDS histogram of u16 locals,
// writes rsqrt(max(deg,1)) floats.
// ---------------------------------------------------------------------------
__global__ __launch_bounds__(256) void outdeg_build(
        const unsigned short* __restrict__ srcb, const int* __restrict__ gcur,
        float* __restrict__ sc_pre, float* __restrict__ sc_nxt) {
    __shared__ int hist[SWSZ];
    int t = threadIdx.x;
    int rel = blockIdx.x / NSW;
    int w = blockIdx.x % NSW;
    int k = rel * NSW + w;
    int segbase = k * CAP_SR;
    int segend = gcur[GC_SRC + k];
    for (int i = t; i < SWSZ; i += 256) hist[i] = 0;
    __syncthreads();
    int cnt = segend - segbase;
    const unsigned* p2 = (const unsigned*)(srcb + segbase);
    int n2 = cnt >> 1;
    for (int i = t; i < n2; i += 256) {
        unsigned v = p2[i];
        atomicAdd(&hist[v & 0xFFFFu], 1);
        atomicAdd(&hist[v >> 16], 1);
    }
    if (t == 0 && (cnt & 1)) atomicAdd(&hist[srcb[segend - 1]], 1);
    __syncthreads();
    float* scp = rel ? sc_nxt : sc_pre;
    int nlo = w * SWSZ;
    int nloc = min(SWSZ, N_JOB - nlo);
    for (int i = t; i < nloc; i += 256) {
        int d = hist[i];
        scp[nlo + i] = rsqrtf((float)(d < 1 ? 1 : d));
    }
}

__device__ __forceinline__ unsigned pack_h2(float a, float b) {
    __half2 h = __float22half2_rn(make_float2(a, b));
    return *reinterpret_cast<unsigned*>(&h);
}
__device__ __forceinline__ float2 unpack_h2(unsigned u) {
    __half2 h = *reinterpret_cast<__half2*>(&u);
    return __half22float2(h);
}

// ---------------------------------------------------------------------------
// Embedding. HOUT=true: fp16 row. HOUT=false: f32 row (hw).
// ---------------------------------------------------------------------------
template <int F, bool HOUT>
__global__ void embed_kernel(const float* __restrict__ feat, const float* __restrict__ W,
                             const float* __restrict__ b, void* __restrict__ outp, int n) {
    __shared__ float Ws[F * 16];
    __shared__ float bs[16];
    int t = threadIdx.x;
    if (t < F * 16) Ws[t] = W[t];
    if (t < 16) bs[t] = b[t];
    __syncthreads();
    int i = blockIdx.x * blockDim.x + t;
    if (i >= n) return;
    float f[F];
#pragma unroll
    for (int k = 0; k < F; k++) f[k] = feat[(size_t)i * F + k];
    float o[16];
#pragma unroll
    for (int d = 0; d < 16; d++) {
        float s = bs[d];
#pragma unroll
        for (int k = 0; k < F; k++) s += f[k] * Ws[k * 16 + d];
        o[d] = s;
    }
    if (HOUT) {
        uint4* dst = (uint4*)((__half*)outp + (size_t)i * 16);
        dst[0] = make_uint4(pack_h2(o[0], o[1]), pack_h2(o[2], o[3]),
                            pack_h2(o[4], o[5]), pack_h2(o[6], o[7]));
        dst[1] = make_uint4(pack_h2(o[8], o[9]), pack_h2(o[10], o[11]),
                            pack_h2(o[12], o[13]), pack_h2(o[14], o[15]));
    } else {
        float4* dst4 = (float4*)((float*)outp + (size_t)i * 16);
        dst4[0] = make_float4(o[0], o[1], o[2], o[3]);
        dst4[1] = make_float4(o[4], o[5], o[6], o[7]);
        dst4[2] = make_float4(o[8], o[9], o[10], o[11]);
        dst4[3] = make_float4(o[12], o[13], o[14], o[15]);
    }
}

__device__ __forceinline__ void mm_accum(const float* __restrict__ Ws, float4 a, int c, float o[4]) {
#pragma unroll
    for (int g = 0; g < 4; ++g) {
        float a0 = __shfl(a.x, g, 4);
        float a1 = __shfl(a.y, g, 4);
        float a2 = __shfl(a.z, g, 4);
        float a3 = __shfl(a.w, g, 4);
        const float* wr = &Ws[(4 * g) * 16 + c * 4];
#pragma unroll
        for (int j = 0; j < 4; ++j)
            o[j] += a0 * wr[j] + a1 * wr[16 + j] + a2 * wr[32 + j] + a3 * wr[48 + j];
    }
}

// ---------------------------------------------------------------------------
// window_layer: one block per 1024-node dst window, 1024 THREADS (16 waves/CU
// at 1 block/CU -> 4x latency hiding vs 256-thread r11; __launch_bounds__
// caps VGPR at 128). acc/res in LDS; sweeps src-group cells in order so all
// resident blocks gather from the same 2MB h16 slice (L2-fitting; FETCH 361MB
// proven in r11). LDS float atomics only. FINAL scores from LDS res.
// ---------------------------------------------------------------------------
template <bool FINAL>
__global__ __launch_bounds__(1024) void window_layer(
        const __half* __restrict__ cur, const float* __restrict__ hwk,
        const unsigned* __restrict__ jjb, const int2* __restrict__ procb,
        const int* __restrict__ gcur,
        const float* __restrict__ sc_pre, const float* __restrict__ sc_nxt,
        const float* __restrict__ Wp, const float* __restrict__ Wn,
        const float* __restrict__ Wng, const float* __restrict__ Wsf,
        const float* __restrict__ bp, const float* __restrict__ bn,
        const float* __restrict__ bsg,
        __half* __restrict__ out, float* __restrict__ scores) {
    __shared__ float acc[DW * 17];     // stride 17: bank-spread for atomics
    __shared__ float res[DW * 16];
    __shared__ int cnt[DW];
    __shared__ float Wl[256];
    __shared__ float bsl[16];
    int t = threadIdx.x;
    int w = blockIdx.x;
    int nlo = w << DWBITS;
    int nloc = min(DW, N_JOB - nlo);
    int c = t & 3, nb = t >> 2;        // nb in [0,256)

    // ---------------- phase A: precede-conv ----------------
    for (int i = t; i < DW * 17; i += 1024) acc[i] = 0.f;
    if (t < DW) cnt[t] = 0;
    if (t < 256) Wl[t] = Wp[t];
    if (t < 16) bsl[t] = bp[t] + bn[t] + bsg[t];
    __syncthreads();
    for (int g = 0; g < G; ++g) {
        int cell = (w << 3) + g;
        int se = gcur[cell];
        for (int p = cell * CAP_JJ + t; p < se; p += 1024) {
            unsigned e = jjb[p];
            int s = (int)(e & 0x7FFFFu);
            int dl = (int)(e >> 19);
            float sc = sc_pre[s];
            const uint4* hp = (const uint4*)(cur + (size_t)s * 16);
            uint4 A = hp[0], B = hp[1];
            float2 f0 = unpack_h2(A.x), f1 = unpack_h2(A.y), f2 = unpack_h2(A.z), f3 = unpack_h2(A.w);
            float2 f4 = unpack_h2(B.x), f5 = unpack_h2(B.y), f6 = unpack_h2(B.z), f7 = unpack_h2(B.w);
            atomicAdd(&cnt[dl], 1);
            float* ap = &acc[dl * 17];
            atomicAdd(ap + 0,  f0.x * sc); atomicAdd(ap + 1,  f0.y * sc);
            atomicAdd(ap + 2,  f1.x * sc); atomicAdd(ap + 3,  f1.y * sc);
            atomicAdd(ap + 4,  f2.x * sc); atomicAdd(ap + 5,  f2.y * sc);
            atomicAdd(ap + 6,  f3.x * sc); atomicAdd(ap + 7,  f3.y * sc);
            atomicAdd(ap + 8,  f4.x * sc); atomicAdd(ap + 9,  f4.y * sc);
            atomicAdd(ap + 10, f5.x * sc); atomicAdd(ap + 11, f5.y * sc);
            atomicAdd(ap + 12, f6.x * sc); atomicAdd(ap + 13, f6.y * sc);
            atomicAdd(ap + 14, f7.x * sc); atomicAdd(ap + 15, f7.y * sc);
        }
        __syncthreads();   // group lockstep
    }
    for (int n = nb; n < nloc; n += 256) {
        float r = rsqrtf((float)(cnt[n] < 1 ? 1 : cnt[n]));
        const float* ap = &acc[n * 17 + c * 4];
        float4 a = make_float4(ap[0] * r, ap[1] * r, ap[2] * r, ap[3] * r);
        float o[4] = {bsl[c * 4 + 0], bsl[c * 4 + 1], bsl[c * 4 + 2], bsl[c * 4 + 3]};
        mm_accum(Wl, a, c, o);
        float* rp = &res[n * 16 + c * 4];
        rp[0] = o[0]; rp[1] = o[1]; rp[2] = o[2]; rp[3] = o[3];
    }
    __syncthreads();

    // ---------------- phase B: next-conv ----------------
    for (int i = t; i < DW * 17; i += 1024) acc[i] = 0.f;
    if (t < DW) cnt[t] = 0;
    if (t < 256) Wl[t] = Wn[t];
    __syncthreads();
    for (int g = 0; g < G; ++g) {
        int cell = NCELL + (w << 3) + g;
        int se = gcur[cell];
        for (int p = cell * CAP_JJ + t; p < se; p += 1024) {
            unsigned e = jjb[p];
            int s = (int)(e & 0x7FFFFu);
            int dl = (int)(e >> 19);
            float sc = sc_nxt[s];
            const uint4* hp = (const uint4*)(cur + (size_t)s * 16);
            uint4 A = hp[0], B = hp[1];
            float2 f0 = unpack_h2(A.x), f1 = unpack_h2(A.y), f2 = unpack_h2(A.z), f3 = unpack_h2(A.w);
            float2 f4 = unpack_h2(B.x), f5 = unpack_h2(B.y), f6 = unpack_h2(B.z), f7 = unpack_h2(B.w);
            atomicAdd(&cnt[dl], 1);
            float* ap = &acc[dl * 17];
            atomicAdd(ap + 0,  f0.x * sc); atomicAdd(ap + 1,  f0.y * sc);
            atomicAdd(ap + 2,  f1.x * sc); atomicAdd(ap + 3,  f1.y * sc);
            atomicAdd(ap + 4,  f2.x * sc); atomicAdd(ap + 5,  f2.y * sc);
            atomicAdd(ap + 6,  f3.x * sc); atomicAdd(ap + 7,  f3.y * sc);
            atomicAdd(ap + 8,  f4.x * sc); atomicAdd(ap + 9,  f4.y * sc);
            atomicAdd(ap + 10, f5.x * sc); atomicAdd(ap + 11, f5.y * sc);
            atomicAdd(ap + 12, f6.x * sc); atomicAdd(ap + 13, f6.y * sc);
            atomicAdd(ap + 14, f7.x * sc); atomicAdd(ap + 15, f7.y * sc);
        }
        __syncthreads();
    }
    for (int n = nb; n < nloc; n += 256) {
        float r = rsqrtf((float)(cnt[n] < 1 ? 1 : cnt[n]));
        const float* ap = &acc[n * 17 + c * 4];
        float4 a = make_float4(ap[0] * r, ap[1] * r, ap[2] * r, ap[3] * r);
        float o[4] = {0.f, 0.f, 0.f, 0.f};
        mm_accum(Wl, a, c, o);
        float* rp = &res[n * 16 + c * 4];
        rp[0] += o[0]; rp[1] += o[1]; rp[2] += o[2]; rp[3] += o[3];
    }
    __syncthreads();

    // ---------------- phase C: sage-mean over workers ----------------
    for (int i = t; i < DW * 17; i += 1024) acc[i] = 0.f;
    if (t < DW) cnt[t] = 0;
    if (t < 256) Wl[t] = Wng[t];
    __syncthreads();
    {
        int sb = w * CAP_PR, se = gcur[GC_PROC + w];
        for (int p = sb + t; p < se; p += 1024) {
            int2 e = procb[p];
            int s = e.x & 0xFFFF, dl = e.x >> 16;
            const float4* hp = (const float4*)(hwk + (size_t)s * 16);
            float4 a0 = hp[0], a1 = hp[1], a2 = hp[2], a3 = hp[3];
            atomicAdd(&cnt[dl], 1);
            float* ap = &acc[dl * 17];
            atomicAdd(ap + 0,  a0.x); atomicAdd(ap + 1,  a0.y);
            atomicAdd(ap + 2,  a0.z); atomicAdd(ap + 3,  a0.w);
            atomicAdd(ap + 4,  a1.x); atomicAdd(ap + 5,  a1.y);
            atomicAdd(ap + 6,  a1.z); atomicAdd(ap + 7,  a1.w);
            atomicAdd(ap + 8,  a2.x); atomicAdd(ap + 9,  a2.y);
            atomicAdd(ap + 10, a2.z); atomicAdd(ap + 11, a2.w);
            atomicAdd(ap + 12, a3.x); atomicAdd(ap + 13, a3.y);
            atomicAdd(ap + 14, a3.z); atomicAdd(ap + 15, a3.w);
        }
    }
    __syncthreads();
    for (int n = nb; n < nloc; n += 256) {
        float r = 1.0f / (float)(cnt[n] < 1 ? 1 : cnt[n]);
        const float* ap = &acc[n * 17 + c * 4];
        float4 a = make_float4(ap[0] * r, ap[1] * r, ap[2] * r, ap[3] * r);
        float o[4] = {0.f, 0.f, 0.f, 0.f};
        mm_accum(Wl, a, c, o);
        float* rp = &res[n * 16 + c * 4];
        rp[0] += o[0]; rp[1] += o[1]; rp[2] += o[2]; rp[3] += o[3];
    }
    __syncthreads();

    // ---------------- phase D: self ----------------
    if (t < 256) Wl[t] = Wsf[t];
    __syncthreads();
    for (int n = nb; n < nloc; n += 256) {
        uint2 raw = *(const uint2*)(cur + (size_t)(nlo + n) * 16 + c * 4);
        float2 lo2 = unpack_h2(raw.x), hi2 = unpack_h2(raw.y);
        float4 a = make_float4(lo2.x, lo2.y, hi2.x, hi2.y);
        float o[4] = {0.f, 0.f, 0.f, 0.f};
        mm_accum(Wl, a, c, o);
        float* rp = &res[n * 16 + c * 4];
        rp[0] += o[0]; rp[1] += o[1]; rp[2] += o[2]; rp[3] += o[3];
    }
    __syncthreads();

    // ---------------- output ----------------
    if (!FINAL) {
        for (int n = nb; n < nloc; n += 256) {
            const float* rp = &res[n * 16 + c * 4];
            *(uint2*)(out + (size_t)(nlo + n) * 16 + c * 4) =
                make_uint2(pack_h2(rp[0], rp[1]), pack_h2(rp[2], rp[3]));
        }
    } else {
        int sb = w * CAP_PR, se = gcur[GC_PROC + w];
        for (int p = sb + t; p < se; p += 1024) {
            int2 e = procb[p];
            int s = e.x & 0xFFFF, dl = e.x >> 16;
            const float4* hp = (const float4*)(hwk + (size_t)s * 16);
            float4 a0 = hp[0], a1 = hp[1], a2 = hp[2], a3 = hp[3];
            const float* rp = &res[dl * 16];
            float d = a0.x * rp[0] + a0.y * rp[1] + a0.z * rp[2] + a0.w * rp[3]
                    + a1.x * rp[4] + a1.y * rp[5] + a1.z * rp[6] + a1.w * rp[7]
                    + a2.x * rp[8] + a2.y * rp[9] + a2.z * rp[10] + a2.w * rp[11]
                    + a3.x * rp[12] + a3.y * rp[13] + a3.z * rp[14] + a3.w * rp[15];
            scores[e.y] = d;
        }
    }
}

extern "C" void kernel_launch(void* const* d_in, const int* in_sizes, int n_in,
                              void* d_out, int out_size, void* d_ws, size_t ws_size,
                              hipStream_t stream) {
    const float* job_feat     = (const float*)d_in[0];
    const float* worker_feat  = (const float*)d_in[1];
    const int*   pre_src      = (const int*)d_in[2];
    const int*   pre_dst      = (const int*)d_in[3];
    const int*   nxt_src      = (const int*)d_in[4];
    const int*   nxt_dst      = (const int*)d_in[5];
    const int*   proc_src     = (const int*)d_in[6];
    const int*   proc_dst     = (const int*)d_in[7];
    const float* W_emb_job    = (const float*)d_in[8];
    const float* b_emb_job    = (const float*)d_in[9];
    const float* W_emb_worker = (const float*)d_in[10];
    const float* b_emb_worker = (const float*)d_in[11];
    const float* W_pre        = (const float*)d_in[12];
    const float* b_pre        = (const float*)d_in[13];
    const float* W_nxt        = (const float*)d_in[14];
    const float* b_nxt        = (const float*)d_in[15];
    const float* W_self       = (const float*)d_in[16];
    const float* W_neigh      = (const float*)d_in[17];
    const float* b_sage       = (const float*)d_in[18];
    float* out = (float*)d_out;

    // Workspace (~97 MB, u32 offsets). srcb aliases h16A/h16B (dead before embed).
    float* ws = (float*)d_ws;
    __half* h16A = (__half*)ws;                              // [0, 4M)
    __half* h16B = (__half*)(ws + 4000000);                  // [4M, 8M)
    float*  hw   = ws + 8000000;                             // [8M, 8.8M)
    float* sc_pre = ws + 8800000;                            // [8.8M, 9.3M)
    float* sc_nxt = ws + 9300000;                            // [9.3M, 9.8M)
    unsigned* jjb = (unsigned*)(ws + 9800000);               // 2*3912*1280 = 10,014,720
    int2*  procb  = (int2*)(ws + 19814720);                  // 489*4608 int2 = 4,506,624 u32
    int*   gcur   = (int*)(ws + 24321344);                   // 8,437 (+pad)
    unsigned short* srcb = (unsigned short*)ws;              // 8,380,416 u16 (aliases h16A/B)

    cursor_init<<<1, 1024, 0, stream>>>(gcur);
    partition_kernel<<<2 * NBJ + NBP, 256, 0, stream>>>(
        pre_src, pre_dst, nxt_src, nxt_dst, proc_src, proc_dst,
        gcur, jjb, procb, srcb);
    outdeg_build<<<2 * NSW, 256, 0, stream>>>(srcb, gcur, sc_pre, sc_nxt);

    embed_kernel<7, true><<<(N_JOB + 255) / 256, 256, 0, stream>>>(
        job_feat, W_emb_job, b_emb_job, h16A, N_JOB);
    embed_kernel<3, false><<<(N_WORKER + 255) / 256, 256, 0, stream>>>(
        worker_feat, W_emb_worker, b_emb_worker, hw, N_WORKER);

    window_layer<false><<<NWD, 1024, 0, stream>>>(
        h16A, hw, jjb, procb, gcur, sc_pre, sc_nxt,
        W_pre, W_nxt, W_neigh, W_self, b_pre, b_nxt, b_sage, h16B, nullptr);
    window_layer<true><<<NWD, 1024, 0, stream>>>(
        h16B, hw, jjb, procb, gcur, sc_pre, sc_nxt,
        W_pre, W_nxt, W_neigh, W_self, b_pre, b_nxt, b_sage, nullptr, out);
}

// Round 13
// 900.688 us; speedup vs baseline: 2.3536x; 2.2993x over previous
//
#include <hip/hip_runtime.h>
#include <hip/hip_fp16.h>

#define N_JOB 500000
#define N_WORKER 50000
#define E_PRE 4000000
#define E_NXT 4000000
#define E_PROC 2000000

// dst/src-window partition: 62 windows x 8192 nodes
#define WBITS 13
#define WSZ 8192
#define NWIN 62                    // ceil(500000/8192)
#define CAP_JJ 67584               // mean 65536 + 8 sigma (sigma ~254)
#define CAP_PR 34000               // mean 32768 + 6.8 sigma
#define CAP_SR 67584

#define EPB 8192                   // edges per partition block
#define NB_PRE ((E_PRE + EPB - 1) / EPB)     // 489
#define NB_PROC ((E_PROC + EPB - 1) / EPB)   // 245

#define NTL(p) __builtin_nontemporal_load(p)

// gcur layout: [0,62) rel0-dst | [62,124) rel1-dst | [124,186) proc-dst
//              [186,248) rel0-src | [248,310) rel1-src
__global__ void cursor_init(int* __restrict__ gcur) {
    int t = threadIdx.x;
    if (t < 2 * NWIN) gcur[t] = t * CAP_JJ;
    else if (t < 3 * NWIN) gcur[t] = (t - 2 * NWIN) * CAP_PR;
    else if (t < 5 * NWIN) gcur[t] = (t - 3 * NWIN) * CAP_SR;
}

// ---------------------------------------------------------------------------
// Partition: each block owns 8192 edges of one relation. LDS histogram by
// window -> one global cursor reservation per (block,segment) -> replay
// writing packed bucket entries with plain stores.
// jj entry: (dst&8191)<<19|src. proc: ((dl<<16)|src, eid). src entry: u16.
// ---------------------------------------------------------------------------
__global__ __launch_bounds__(256) void partition_kernel(
        const int* __restrict__ pre_src, const int* __restrict__ pre_dst,
        const int* __restrict__ nxt_src, const int* __restrict__ nxt_dst,
        const int* __restrict__ proc_src, const int* __restrict__ proc_dst,
        int* __restrict__ gcur, unsigned* __restrict__ jjb,
        int2* __restrict__ procb, unsigned short* __restrict__ srcb) {
    __shared__ int cntD[NWIN], cntS[NWIN], basD[NWIN], basS[NWIN];
    __shared__ int curD[NWIN], curS[NWIN];
    int t = threadIdx.x;
    int b = blockIdx.x;
    int rel, lo, hi;
    const int *dstp, *srcp;
    if (b < NB_PRE) {
        rel = 0; dstp = pre_dst; srcp = pre_src;
        lo = b * EPB; hi = min(lo + EPB, E_PRE);
    } else if (b < 2 * NB_PRE) {
        rel = 1; b -= NB_PRE; dstp = nxt_dst; srcp = nxt_src;
        lo = b * EPB; hi = min(lo + EPB, E_NXT);
    } else {
        rel = 2; b -= 2 * NB_PRE; dstp = proc_dst; srcp = proc_src;
        lo = b * EPB; hi = min(lo + EPB, E_PROC);
    }
    if (t < NWIN) { cntD[t] = 0; cntS[t] = 0; }
    __syncthreads();
    if (rel < 2) {
        for (int i = lo + t; i < hi; i += 256) {
            atomicAdd(&cntD[dstp[i] >> WBITS], 1);
            atomicAdd(&cntS[srcp[i] >> WBITS], 1);
        }
        __syncthreads();
        if (t < NWIN) {
            int c = cntD[t];
            basD[t] = c ? atomicAdd(&gcur[rel * NWIN + t], c) : 0;
            c = cntS[t];
            basS[t] = c ? atomicAdd(&gcur[3 * NWIN + rel * NWIN + t], c) : 0;
            curD[t] = 0; curS[t] = 0;
        }
        __syncthreads();
        for (int i = lo + t; i < hi; i += 256) {
            int d = dstp[i], s = srcp[i];
            int wd = d >> WBITS, wsw = s >> WBITS;
            int pD = basD[wd] + atomicAdd(&curD[wd], 1);
            jjb[pD] = ((unsigned)(d & (WSZ - 1)) << 19) | (unsigned)s;
            int pS = basS[wsw] + atomicAdd(&curS[wsw], 1);
            srcb[pS] = (unsigned short)(s & (WSZ - 1));
        }
    } else {
        for (int i = lo + t; i < hi; i += 256)
            atomicAdd(&cntD[dstp[i] >> WBITS], 1);
        __syncthreads();
        if (t < NWIN) {
            int c = cntD[t];
            basD[t] = c ? atomicAdd(&gcur[2 * NWIN + t], c) : 0;
            curD[t] = 0;
        }
        __syncthreads();
        for (int i = lo + t; i < hi; i += 256) {
            int d = dstp[i], s = srcp[i];
            int wd = d >> WBITS;
            int pD = basD[wd] + atomicAdd(&curD[wd], 1);
            procb[pD] = make_int2(((d & (WSZ - 1)) << 16) | s, i);
        }
    }
}

// ---------------------------------------------------------------------------
// csr_build: one block per (rel,window). Fuses count + scan + place with LDS
// only; writes row ENDS + scatters into own contiguous adj region.
// ---------------------------------------------------------------------------
__global__ __launch_bounds__(256) void csr_build(
        const unsigned* __restrict__ jjb, const int2* __restrict__ procb,
        const int* __restrict__ gcur, int* __restrict__ off,
        int* __restrict__ adj_jj, int2* __restrict__ adj_proc) {
    __shared__ int hist[WSZ];
    __shared__ int scanB[WSZ];
    __shared__ int part[256];
    __shared__ int wcnt[NWIN];
    __shared__ int baseS;
    int t = threadIdx.x;
    int rel = blockIdx.x / NWIN;
    int w = blockIdx.x % NWIN;
    int segbase, segend;
    if (rel < 2) { int k = rel * NWIN + w; segbase = k * CAP_JJ; segend = gcur[k]; }
    else         { segbase = w * CAP_PR; segend = gcur[2 * NWIN + w]; }
    if (t < NWIN) {
        if (rel < 2) wcnt[t] = gcur[rel * NWIN + t] - (rel * NWIN + t) * CAP_JJ;
        else         wcnt[t] = gcur[2 * NWIN + t] - t * CAP_PR;
    }
    for (int i = t; i < WSZ; i += 256) hist[i] = 0;
    __syncthreads();
    if (t == 0) {
        int bb = (rel == 1) ? E_PRE : 0;
        for (int i = 0; i < w; ++i) bb += wcnt[i];
        baseS = bb;
    }
    if (rel < 2) {
        for (int p = segbase + t; p < segend; p += 256)
            atomicAdd(&hist[jjb[p] >> 19], 1);
    } else {
        for (int p = segbase + t; p < segend; p += 256)
            atomicAdd(&hist[procb[p].x >> 16], 1);
    }
    __syncthreads();
    {
        int mb = t * 32;
        int sum = 0;
        for (int j = 0; j < 32; ++j) { int v = hist[mb + j]; scanB[mb + j] = sum; sum += v; }
        part[t] = sum;
        __syncthreads();
        if (t == 0) { int r = 0; for (int i = 0; i < 256; ++i) { int v = part[i]; part[i] = r; r += v; } }
        __syncthreads();
        int add = part[t] + baseS;
        for (int j = 0; j < 32; ++j) scanB[mb + j] += add;
    }
    __syncthreads();
    int nlo = w * WSZ;
    int nloc = min(WSZ, N_JOB - nlo);
    for (int i = t; i < nloc; i += 256)
        off[rel * N_JOB + nlo + i] = scanB[i] + hist[i];   // row ENDS
    __syncthreads();
    if (rel < 2) {
        for (int p = segbase + t; p < segend; p += 256) {
            unsigned e = jjb[p];
            int slot = atomicAdd(&scanB[e >> 19], 1);
            adj_jj[slot] = (int)(e & 0x7FFFFu);
        }
    } else {
        for (int p = segbase + t; p < segend; p += 256) {
            int2 e = procb[p];
            int slot = atomicAdd(&scanB[e.x >> 16], 1);
            adj_proc[slot] = make_int2(e.x & 0xFFFF, e.y);
        }
    }
}

// ---------------------------------------------------------------------------
// outdeg_build: one block per (rel,window); LDS histogram of u16 src-locals,
// writes rsqrt(max(deg,1)) floats directly.
// ---------------------------------------------------------------------------
__global__ __launch_bounds__(256) void outdeg_build(
        const unsigned short* __restrict__ srcb, const int* __restrict__ gcur,
        float* __restrict__ sc_pre, float* __restrict__ sc_nxt) {
    __shared__ int hist[WSZ];
    int t = threadIdx.x;
    int rel = blockIdx.x / NWIN;
    int w = blockIdx.x % NWIN;
    int k = rel * NWIN + w;
    int segbase = k * CAP_SR;
    int segend = gcur[3 * NWIN + k];
    for (int i = t; i < WSZ; i += 256) hist[i] = 0;
    __syncthreads();
    int cnt = segend - segbase;
    const unsigned* p2 = (const unsigned*)(srcb + segbase);
    int n2 = cnt >> 1;
    for (int i = t; i < n2; i += 256) {
        unsigned v = p2[i];
        atomicAdd(&hist[v & 0xFFFFu], 1);
        atomicAdd(&hist[v >> 16], 1);
    }
    if (t == 0 && (cnt & 1)) atomicAdd(&hist[srcb[segend - 1]], 1);
    __syncthreads();
    float* scp = rel ? sc_nxt : sc_pre;
    int nlo = w * WSZ;
    int nloc = min(WSZ, N_JOB - nlo);
    for (int i = t; i < nloc; i += 256) {
        int d = hist[i];
        scp[nlo + i] = rsqrtf((float)(d < 1 ? 1 : d));
    }
}

__device__ __forceinline__ unsigned pack_h2(float a, float b) {
    __half2 h = __float22half2_rn(make_float2(a, b));
    return *reinterpret_cast<unsigned*>(&h);
}
__device__ __forceinline__ float2 unpack_h2(unsigned u) {
    __half2 h = *reinterpret_cast<__half2*>(&u);
    return __half22float2(h);
}

// ---------------------------------------------------------------------------
// Embedding. HOUT=true: write fp16 row (16 halfs). HOUT=false: f32 row (hw).
// ---------------------------------------------------------------------------
template <int F, bool HOUT>
__global__ void embed_kernel(const float* __restrict__ feat, const float* __restrict__ W,
                             const float* __restrict__ b, void* __restrict__ outp, int n) {
    __shared__ float Ws[F * 16];
    __shared__ float bs[16];
    int t = threadIdx.x;
    if (t < F * 16) Ws[t] = W[t];
    if (t < 16) bs[t] = b[t];
    __syncthreads();
    int i = blockIdx.x * blockDim.x + t;
    if (i >= n) return;
    float f[F];
#pragma unroll
    for (int k = 0; k < F; k++) f[k] = feat[(size_t)i * F + k];
    float o[16];
#pragma unroll
    for (int d = 0; d < 16; d++) {
        float s = bs[d];
#pragma unroll
        for (int k = 0; k < F; k++) s += f[k] * Ws[k * 16 + d];
        o[d] = s;
    }
    if (HOUT) {
        uint4* dst = (uint4*)((__half*)outp + (size_t)i * 16);
        dst[0] = make_uint4(pack_h2(o[0], o[1]), pack_h2(o[2], o[3]),
                            pack_h2(o[4], o[5]), pack_h2(o[6], o[7]));
        dst[1] = make_uint4(pack_h2(o[8], o[9]), pack_h2(o[10], o[11]),
                            pack_h2(o[12], o[13]), pack_h2(o[14], o[15]));
    } else {
        float4* dst4 = (float4*)((float*)outp + (size_t)i * 16);
        dst4[0] = make_float4(o[0], o[1], o[2], o[3]);
        dst4[1] = make_float4(o[4], o[5], o[6], o[7]);
        dst4[2] = make_float4(o[8], o[9], o[10], o[11]);
        dst4[3] = make_float4(o[12], o[13], o[14], o[15]);
    }
}

// ---------------------------------------------------------------------------
// Merged per-layer gather, fp16 rows, 4-wide unrolled walks (8 outstanding
// random loads per lane). adj/off streams nontemporal so they evict first
// and preserve h16 L2 residency. FINAL writes scores only.
// ---------------------------------------------------------------------------
__device__ __forceinline__ void mm_accum(const float* __restrict__ Ws, float4 a, int c, float o[4]) {
#pragma unroll
    for (int g = 0; g < 4; ++g) {
        float a0 = __shfl(a.x, g, 4);
        float a1 = __shfl(a.y, g, 4);
        float a2 = __shfl(a.z, g, 4);
        float a3 = __shfl(a.w, g, 4);
        const float* wr = &Ws[(4 * g) * 16 + c * 4];
#pragma unroll
        for (int j = 0; j < 4; ++j)
            o[j] += a0 * wr[j] + a1 * wr[16 + j] + a2 * wr[32 + j] + a3 * wr[48 + j];
    }
}

__device__ __forceinline__ float4 load_h16(const __half* __restrict__ h16, int row, int c) {
    uint2 raw = *(const uint2*)(h16 + (size_t)row * 16 + c * 4);
    float2 lo = unpack_h2(raw.x), hi = unpack_h2(raw.y);
    return make_float4(lo.x, lo.y, hi.x, hi.y);
}

__device__ __forceinline__ void walk_jj(const __half* __restrict__ cur,
                                        const int* __restrict__ adj_jj,
                                        const float* __restrict__ scv,
                                        int s0, int e0, int c, float4& acc) {
    int p = s0;
    for (; p + 3 < e0; p += 4) {
        int sa = NTL(adj_jj + p),     sb = NTL(adj_jj + p + 1);
        int sc2 = NTL(adj_jj + p + 2), sd = NTL(adj_jj + p + 3);
        float wa = scv[sa], wb = scv[sb], wc = scv[sc2], wd = scv[sd];
        float4 ha = load_h16(cur, sa, c);
        float4 hb = load_h16(cur, sb, c);
        float4 hc = load_h16(cur, sc2, c);
        float4 hd = load_h16(cur, sd, c);
        acc.x += ha.x * wa + hb.x * wb + hc.x * wc + hd.x * wd;
        acc.y += ha.y * wa + hb.y * wb + hc.y * wc + hd.y * wd;
        acc.z += ha.z * wa + hb.z * wb + hc.z * wc + hd.z * wd;
        acc.w += ha.w * wa + hb.w * wb + hc.w * wc + hd.w * wd;
    }
    for (; p < e0; ++p) {
        int sa = NTL(adj_jj + p);
        float wa = scv[sa];
        float4 ha = load_h16(cur, sa, c);
        acc.x += ha.x * wa; acc.y += ha.y * wa; acc.z += ha.z * wa; acc.w += ha.w * wa;
    }
}

template <bool FINAL>
__global__ void gather_layer(const __half* __restrict__ cur, const float* __restrict__ hwk,
                             const int* __restrict__ adj_jj, const int2* __restrict__ adj_proc,
                             const int* __restrict__ off,
                             const float* __restrict__ sc_pre, const float* __restrict__ sc_nxt,
                             const float* __restrict__ Wp, const float* __restrict__ Wn,
                             const float* __restrict__ Wng, const float* __restrict__ Wsf,
                             const float* __restrict__ bp, const float* __restrict__ bn,
                             const float* __restrict__ bsg,
                             __half* __restrict__ out, float* __restrict__ scores) {
    __shared__ float WpS[256], WnS[256], WngS[256], WsfS[256], bs[16];
    int t = threadIdx.x;
    WpS[t] = Wp[t]; WnS[t] = Wn[t]; WngS[t] = Wng[t]; WsfS[t] = Wsf[t];
    if (t < 16) bs[t] = bp[t] + bn[t] + bsg[t];
    __syncthreads();
    unsigned gid = blockIdx.x * 256 + t;
    unsigned v = gid >> 2, c = gid & 3;
    if (v >= N_JOB) return;
    const int* rend0 = off;
    const int* rend1 = off + N_JOB;
    const int* rend2 = off + 2 * N_JOB;
    int e0 = NTL(rend0 + v), s0 = v ? NTL(rend0 + v - 1) : 0;
    int e1 = NTL(rend1 + v), s1 = v ? NTL(rend1 + v - 1) : E_PRE;
    int e2 = NTL(rend2 + v), s2 = v ? NTL(rend2 + v - 1) : 0;

    float4 accP = make_float4(0.f, 0.f, 0.f, 0.f);
    walk_jj(cur, adj_jj, sc_pre, s0, e0, c, accP);
    float4 accN = make_float4(0.f, 0.f, 0.f, 0.f);
    walk_jj(cur, adj_jj, sc_nxt, s1, e1, c, accN);

    float4 accS = make_float4(0.f, 0.f, 0.f, 0.f);
    {
        int p = s2;
        for (; p + 1 < e2; p += 2) {
            int sa = adj_proc[p].x, sb = adj_proc[p + 1].x;
            float4 ha = ((const float4*)(hwk + (size_t)sa * 16))[c];
            float4 hb = ((const float4*)(hwk + (size_t)sb * 16))[c];
            accS.x += ha.x + hb.x; accS.y += ha.y + hb.y;
            accS.z += ha.z + hb.z; accS.w += ha.w + hb.w;
        }
        if (p < e2) {
            int sa = adj_proc[p].x;
            float4 ha = ((const float4*)(hwk + (size_t)sa * 16))[c];
            accS.x += ha.x; accS.y += ha.y; accS.z += ha.z; accS.w += ha.w;
        }
    }

    int d0 = e0 - s0, d1 = e1 - s1, d2 = e2 - s2;
    float rp = rsqrtf((float)(d0 < 1 ? 1 : d0));
    float rn = rsqrtf((float)(d1 < 1 ? 1 : d1));
    float ri = 1.0f / (float)(d2 < 1 ? 1 : d2);
    accP.x *= rp; accP.y *= rp; accP.z *= rp; accP.w *= rp;
    accN.x *= rn; accN.y *= rn; accN.z *= rn; accN.w *= rn;
    accS.x *= ri; accS.y *= ri; accS.z *= ri; accS.w *= ri;

    float o[4];
#pragma unroll
    for (int j = 0; j < 4; ++j) o[j] = bs[c * 4 + j];
    mm_accum(WpS, accP, c, o);
    mm_accum(WnS, accN, c, o);
    mm_accum(WngS, accS, c, o);
    float4 hself = load_h16(cur, v, c);
    mm_accum(WsfS, hself, c, o);

    if (!FINAL) {
        uint2* dst = (uint2*)(out + (size_t)v * 16 + c * 4);
        *dst = make_uint2(pack_h2(o[0], o[1]), pack_h2(o[2], o[3]));
    } else {
        for (int p = s2; p < e2; ++p) {
            int2 pr = adj_proc[p];
            float4 wv = ((const float4*)(hwk + (size_t)pr.x * 16))[c];
            float d = o[0] * wv.x + o[1] * wv.y + o[2] * wv.z + o[3] * wv.w;
            d += __shfl_xor(d, 1, 4);
            d += __shfl_xor(d, 2, 4);
            if (c == 0) scores[pr.y] = d;
        }
    }
}

extern "C" void kernel_launch(void* const* d_in, const int* in_sizes, int n_in,
                              void* d_out, int out_size, void* d_ws, size_t ws_size,
                              hipStream_t stream) {
    const float* job_feat     = (const float*)d_in[0];
    const float* worker_feat  = (const float*)d_in[1];
    const int*   pre_src      = (const int*)d_in[2];
    const int*   pre_dst      = (const int*)d_in[3];
    const int*   nxt_src      = (const int*)d_in[4];
    const int*   nxt_dst      = (const int*)d_in[5];
    const int*   proc_src     = (const int*)d_in[6];
    const int*   proc_dst     = (const int*)d_in[7];
    const float* W_emb_job    = (const float*)d_in[8];
    const float* b_emb_job    = (const float*)d_in[9];
    const float* W_emb_worker = (const float*)d_in[10];
    const float* b_emb_worker = (const float*)d_in[11];
    const float* W_pre        = (const float*)d_in[12];
    const float* b_pre        = (const float*)d_in[13];
    const float* W_nxt        = (const float*)d_in[14];
    const float* b_nxt        = (const float*)d_in[15];
    const float* W_self       = (const float*)d_in[16];
    const float* W_neigh      = (const float*)d_in[17];
    const float* b_sage       = (const float*)d_in[18];
    float* out = (float*)d_out;

    // Workspace (~125 MB). fp16 h buffers + hw alias the dead bucket region.
    float* ws = (float*)d_ws;
    __half* h16A = (__half*)ws;                         // 8M halfs = 4M u32
    __half* h16B = (__half*)(ws + 4000000);             // 8M halfs = 4M u32
    float*  hw   = ws + 8000000;                        //   800,000 f
    unsigned* jjb = (unsigned*)ws;                      // 124*67584 = 8,380,416 u32
    int2*  procb  = (int2*)(ws + 8380416);              // 62*34000 int2
    unsigned short* srcb = (unsigned short*)(ws + 12596416); // 124*67584 u16
    int*   off  = (int*)(ws + 16800000);                // 1,500,000 (row ends)
    int*   gcur = off + 3 * N_JOB;                      // 512
    int*   adj_jj = gcur + 512;                         // 8,000,000
    int2*  adj_proc = (int2*)(adj_jj + 8000000);        // 2,000,000 int2
    float* sc_pre = (float*)(adj_proc + 2000000);       // 500,000
    float* sc_nxt = sc_pre + N_JOB;                     // 500,000

    cursor_init<<<1, 512, 0, stream>>>(gcur);
    partition_kernel<<<2 * NB_PRE + NB_PROC, 256, 0, stream>>>(
        pre_src, pre_dst, nxt_src, nxt_dst, proc_src, proc_dst,
        gcur, jjb, procb, srcb);
    csr_build<<<3 * NWIN, 256, 0, stream>>>(jjb, procb, gcur, off, adj_jj, adj_proc);
    outdeg_build<<<2 * NWIN, 256, 0, stream>>>(srcb, gcur, sc_pre, sc_nxt);

    embed_kernel<7, true><<<(N_JOB + 255) / 256, 256, 0, stream>>>(
        job_feat, W_emb_job, b_emb_job, h16A, N_JOB);
    embed_kernel<3, false><<<(N_WORKER + 255) / 256, 256, 0, stream>>>(
        worker_feat, W_emb_worker, b_emb_worker, hw, N_WORKER);

    const int GGRID = (4 * N_JOB + 255) / 256;
    gather_layer<false><<<GGRID, 256, 0, stream>>>(
        h16A, hw, adj_jj, adj_proc, off, sc_pre, sc_nxt,
        W_pre, W_nxt, W_neigh, W_self, b_pre, b_nxt, b_sage, h16B, nullptr);
    gather_layer<true><<<GGRID, 256, 0, stream>>>(
        h16B, hw, adj_jj, adj_proc, off, sc_pre, sc_nxt,
        W_pre, W_nxt, W_neigh, W_self, b_pre, b_nxt, b_sage, nullptr, out);
}